// Round 6
// baseline (293.531 us; speedup 1.0000x reference)
//
#include <hip/hip_runtime.h>
#include <hip/hip_bf16.h>
#include <cstdint>
#include <cstddef>

// B=4, S=2048, D=1024. Inputs fp32 (runtime-detected, bf16 path kept).
// Round-13: GEMM schedules frozen (r11 engines, the measured best of 5
// attempts: all land 650-730 TF). This round attacks the ~100us of
// non-GEMM time: wave-per-row softmax and resid+LN (no LDS/barrier
// reductions, 64B/lane loads), and XCD-chunked block swizzle on proj (T1).
//   proj (gemm128 2-phase body, 3 blocks/CU, XCD-chunk swizzle, 1536 blocks):
//     logical id = (bid&7)*192 + (bid>>3): each XCD gets 192 contiguous tiles
//     [0,1024):  QK2[8192][2048] = Xb @ Wt(q,k)^T + [bq|bk]
//     [1024,1536): Vt[1024][8192] = Wv^T @ Xb^T + bv  (V^T direct; no transpose)
//   QK^T / PV: r11 gemm256r (256x256 ring-2, 1 barrier/iter) verbatim.
//   PV split-K2 -> partial sums in dead Q|K slots of QK2; LN sums halves.
// Launches (6): prep, proj, QK^T, softmax, PV, resid_ln.
//
// d_ws layout (16B-aligned, ~107 MB):
//   bias5 @ 16           10,240   (bq|bk|bv|gamma|beta bf16)
//   Wt    @ 16,384       6,291,456   ([3][1024][1024]: q,k,v; [d_out][k])
//   QK2   @ 6,307,840    33,554,432  ([8192][2048]: Q|K, later Ctx0|Ctx1)
//   Xb    @ 39,862,272   16,777,216
//   S4/P4 @ 56,639,488   33,554,432
//   Vt    @ 90,193,920   16,777,216  ([1024][8192], batch b at col 2048b)

typedef unsigned short u16;
using bf16x8 = __attribute__((ext_vector_type(8))) short;
using f32x16 = __attribute__((ext_vector_type(16))) float;

typedef __attribute__((address_space(3))) unsigned int lds_uint;
typedef const __attribute__((address_space(1))) unsigned int glob_uint;

__device__ __forceinline__ float bf2f(u16 h) {
    union { unsigned int u; float f; } c;
    c.u = ((unsigned int)h) << 16;
    return c.f;
}
__device__ __forceinline__ u16 f2bf(float f) {
    union { float f; unsigned int u; } c;
    c.f = f;
    return (u16)((c.u + 0x7fffu + ((c.u >> 16) & 1u)) >> 16);  // RNE
}
__device__ __forceinline__ void load_lds16(const void* g, void* l) {
    __builtin_amdgcn_global_load_lds((glob_uint*)g, (lds_uint*)l, 16, 0, 0);
}

// Inline dtype detection: even-index u16s of X decode as bf16 to small finite
// nonzero values iff X is bf16; fp32 mantissa halves produce huge/NaN decodes.
__device__ __forceinline__ int detect_fp32(const u16* X, int* sflag) {
    const int t = threadIdx.x;
    if (t < 64) {
        bool bad = false, nz = false;
#pragma unroll
        for (int j = 0; j < 4; ++j) {
            float v = bf2f(X[(t * 4 + j) * 2]);
            if (!(fabsf(v) <= 1e9f)) bad = true;
            if (v != 0.f) nz = true;
        }
        unsigned long long ab = __ballot(bad);
        unsigned long long an = __ballot(nz);
        if (t == 0) *sflag = (ab != 0ull || an == 0ull) ? 1 : 0;
    }
    __syncthreads();
    return *sflag;
}

// ------------------------------------------------------------------- prep
__global__ __launch_bounds__(256) void prep_kernel(
    const void* __restrict__ X, const void* __restrict__ Wq,
    const void* __restrict__ Wk, const void* __restrict__ Wv,
    const void* __restrict__ bq, const void* __restrict__ bk,
    const void* __restrict__ bv, const void* __restrict__ gamma,
    const void* __restrict__ beta,
    u16* __restrict__ Xb, u16* __restrict__ Wt, u16* __restrict__ bias5)
{
    __shared__ u16 tile[64][72];
    __shared__ int sflag;
    const int fp32 = detect_fp32((const u16*)X, &sflag);
    const int t   = threadIdx.x;
    const int blk = blockIdx.x;

    if (blk < 4096) {                       // ---- convert X
        const size_t i = ((size_t)blk * 256 + t) * 8;
        if (fp32) {
            const float* f = (const float*)X;
            float4 a = *(const float4*)(f + i);
            float4 b = *(const float4*)(f + i + 4);
            ushort4 o0, o1;
            o0.x = f2bf(a.x); o0.y = f2bf(a.y); o0.z = f2bf(a.z); o0.w = f2bf(a.w);
            o1.x = f2bf(b.x); o1.y = f2bf(b.y); o1.z = f2bf(b.z); o1.w = f2bf(b.w);
            *(ushort4*)(Xb + i) = o0;
            *(ushort4*)(Xb + i + 4) = o1;
        } else {
            *(uint4*)(Xb + i) = *(const uint4*)((const u16*)X + i);
        }
    } else if (blk < 4864) {                // ---- transpose W
        const int idx = blk - 4096;
        const int k0 = (idx & 15) * 64;
        const int n0 = ((idx >> 4) & 15) * 64;
        const int w  = idx >> 8;
        const void* W = (w == 0) ? Wq : ((w == 1) ? Wk : Wv);
#pragma unroll
        for (int it = 0; it < 2; ++it) {
            int i2 = t + it * 256;
            int r = i2 >> 3;
            int c = (i2 & 7) * 8;
            const size_t off = (size_t)(k0 + r) * 1024 + n0 + c;
            if (fp32) {
                const float* Wf = (const float*)W + off;
                float4 a = *(const float4*)Wf;
                float4 b = *(const float4*)(Wf + 4);
                u16* tp = &tile[r][c];
                tp[0] = f2bf(a.x); tp[1] = f2bf(a.y); tp[2] = f2bf(a.z); tp[3] = f2bf(a.w);
                tp[4] = f2bf(b.x); tp[5] = f2bf(b.y); tp[6] = f2bf(b.z); tp[7] = f2bf(b.w);
            } else {
                *(uint4*)&tile[r][c] = *(const uint4*)((const u16*)W + off);
            }
        }
        __syncthreads();
#pragma unroll
        for (int it = 0; it < 2; ++it) {
            int i2 = t + it * 256;
            int r = i2 >> 3;
            int c = (i2 & 7) * 8;
            union { u16 s[8]; uint4 v; } tmp;
#pragma unroll
            for (int j = 0; j < 8; ++j) tmp.s[j] = tile[c + j][r];
            *(uint4*)(Wt + (size_t)(w * 1024 + n0 + r) * 1024 + k0 + c) = tmp.v;
        }
    } else {                                // ---- small vectors
        const int v = blk - 4864;
        const void* srcs[5] = {bq, bk, bv, gamma, beta};
        const void* src = srcs[v];
        u16* d = bias5 + (size_t)v * 1024;
        const int i = t * 4;
        if (fp32) {
            const float* f = (const float*)src;
            ushort4 o;
            o.x = f2bf(f[i]); o.y = f2bf(f[i + 1]);
            o.z = f2bf(f[i + 2]); o.w = f2bf(f[i + 3]);
            *(ushort4*)(d + i) = o;
        } else {
            *(ushort4*)(d + i) = *(const ushort4*)((const u16*)src + i);
        }
    }
}

// ------------------------------------------------- proj: QK gemm + V^T gemm
// Round-6 verified gemm128 body. XCD-chunk swizzle: physical bid round-robins
// XCDs, so logical id = (bid&7)*192 + (bid>>3) gives each XCD 192 contiguous
// tiles (L2 panel reuse). 1536 logical blocks:
//   [0,1024):    QK2 = Xb @ Wt(qk)^T + bias[col]   (16 n-tiles x 64 m-tiles)
//   [1024,1536): Vt  = Wvt @ Xb^T   + bias[row]    (64 n-tiles x  8 m-tiles)
__global__ __launch_bounds__(256) void proj_kernel(
    const u16* __restrict__ Xb, const u16* __restrict__ Wt,
    u16* __restrict__ QK2, u16* __restrict__ Vt, const u16* __restrict__ bias5)
{
    __shared__ u16 As[2][128 * 32];
    __shared__ u16 Bs[2][128 * 32];
    const int bid  = blockIdx.x;
    const int id   = (bid & 7) * 192 + (bid >> 3);   // bijective: 1536 = 8*192
    const bool vt  = (id >= 1024);
    const u16* A;  const u16* Bt;  u16* C;
    int lda, ldb, ldc, m0, n0;
    if (!vt) {
        A = Xb;  lda = 1024;  Bt = Wt;  ldb = 1024;  C = QK2;  ldc = 2048;
        n0 = (id & 15) * 128;  m0 = (id >> 4) * 128;
    } else {
        const int i2 = id - 1024;
        A = Wt + (size_t)2 * 1024 * 1024;  lda = 1024;   // Wv^T [d][k]
        Bt = Xb;  ldb = 1024;  C = Vt;  ldc = 8192;
        n0 = (i2 & 63) * 128;  m0 = (i2 >> 6) * 128;
    }
    const int t    = threadIdx.x;
    const int lane = t & 63;
    const int w    = t >> 6;
    const int wr   = w >> 1, wc = w & 1;

    // swizzled staging (wave w covers rows [w*32, w*32+32)); key = (srow>>1)&3
    const int srow = lane >> 2;
    const int skg  = (lane & 3) ^ ((srow >> 1) & 3);
    const u16* Ag0 = A  + (size_t)(m0 + w * 32 +      srow) * lda + skg * 8;
    const u16* Ag1 = A  + (size_t)(m0 + w * 32 + 16 + srow) * lda + skg * 8;
    const u16* Bg0 = Bt + (size_t)(n0 + w * 32 +      srow) * ldb + skg * 8;
    const u16* Bg1 = Bt + (size_t)(n0 + w * 32 + 16 + srow) * ldb + skg * 8;
    u16* Al0 = &As[0][(w * 32) * 32];
    u16* Al1 = &As[1][(w * 32) * 32];
    u16* Bl0 = &Bs[0][(w * 32) * 32];
    u16* Bl1 = &Bs[1][(w * 32) * 32];

    f32x16 acc[2][2];
#pragma unroll
    for (int mi = 0; mi < 2; ++mi)
#pragma unroll
        for (int ni = 0; ni < 2; ++ni)
#pragma unroll
            for (int r = 0; r < 16; ++r)
                acc[mi][ni][r] = 0.f;

    const int ml  = lane & 31;
    const int kh  = lane >> 5;
    const int key = (ml >> 1) & 3;

    for (int k0 = 0; k0 < 1024; k0 += 64) {
        load_lds16(Ag0 + k0,      Al0);
        load_lds16(Ag1 + k0,      Al0 + 16 * 32);
        load_lds16(Bg0 + k0,      Bl0);
        load_lds16(Bg1 + k0,      Bl0 + 16 * 32);
        load_lds16(Ag0 + k0 + 32, Al1);
        load_lds16(Ag1 + k0 + 32, Al1 + 16 * 32);
        load_lds16(Bg0 + k0 + 32, Bl1);
        load_lds16(Bg1 + k0 + 32, Bl1 + 16 * 32);
        __syncthreads();
#pragma unroll
        for (int slab = 0; slab < 2; ++slab) {
            const u16* as_ = As[slab];
            const u16* bs_ = Bs[slab];
#pragma unroll
            for (int s = 0; s < 2; ++s) {
                const int g    = s * 2 + kh;
                const int slot = (g ^ key) * 8;
                bf16x8 a0 = *(const bf16x8*)&as_[(wr * 64 +      ml) * 32 + slot];
                bf16x8 a1 = *(const bf16x8*)&as_[(wr * 64 + 32 + ml) * 32 + slot];
                bf16x8 b0 = *(const bf16x8*)&bs_[(wc * 64 +      ml) * 32 + slot];
                bf16x8 b1 = *(const bf16x8*)&bs_[(wc * 64 + 32 + ml) * 32 + slot];
                acc[0][0] = __builtin_amdgcn_mfma_f32_32x32x16_bf16(a0, b0, acc[0][0], 0, 0, 0);
                acc[0][1] = __builtin_amdgcn_mfma_f32_32x32x16_bf16(a0, b1, acc[0][1], 0, 0, 0);
                acc[1][0] = __builtin_amdgcn_mfma_f32_32x32x16_bf16(a1, b0, acc[1][0], 0, 0, 0);
                acc[1][1] = __builtin_amdgcn_mfma_f32_32x32x16_bf16(a1, b1, acc[1][1], 0, 0, 0);
            }
        }
        __syncthreads();
    }

    // C/D layout (m74/m101): col = lane&31, row = (r&3) + 8*(r>>2) + 4*(lane>>5)
    const int colb = n0 + wc * 64 + ml;
    const int rowb = m0 + wr * 64 + 4 * kh;
#pragma unroll
    for (int mi = 0; mi < 2; ++mi) {
#pragma unroll
        for (int ni = 0; ni < 2; ++ni) {
            const int col = colb + ni * 32;
            const float cbias = vt ? 0.f : bf2f(bias5[col]);
#pragma unroll
            for (int r = 0; r < 16; ++r) {
                const int row = rowb + mi * 32 + (r & 3) + 8 * (r >> 2);
                const float bias = vt ? bf2f(bias5[2048 + row]) : cbias;
                C[(size_t)row * ldc + col] = f2bf(acc[mi][ni][r] + bias);
            }
        }
    }
}

// --------------------------------------- GEMM 256x256, K64 ring-2, 1 barrier
// (round-11 verbatim - the measured best QK^T/PV engine)
template<int EPI, int KSPLIT>
__global__ __launch_bounds__(512, 2) void gemm256r(
    const u16* __restrict__ A, int lda, size_t sA,
    const u16* __restrict__ Bt, int ldb, size_t sB,
    u16* __restrict__ C, int ldc, size_t sC,
    int K, float scale, const u16* __restrict__ bias3)
{
    __shared__ u16 As[2][256 * 64];     // 64 KB
    __shared__ u16 Bs[2][256 * 64];     // 64 KB

    const int t  = threadIdx.x;
    const int l  = t & 63;
    const int w  = t >> 6;              // 0..7
    const int wm = w >> 2;              // 0..1
    const int wn = w & 3;               // 0..3
    const int m0 = blockIdx.y * 256;
    const int n0 = blockIdx.x * 256;
    const int batch = (int)blockIdx.z >> (KSPLIT - 1);
    const int ks    = (int)blockIdx.z & (KSPLIT - 1);
    A  += (size_t)batch * sA + (size_t)ks * K;
    Bt += (size_t)batch * sB + (size_t)ks * K;
    C  += (size_t)batch * sC + (size_t)ks * 1024;   // ks==0 when KSPLIT==1

    // ---- staging constants (pre-swizzled global source, linear LDS dest)
    const int srow = w * 8 + (l >> 3);              // row within 64-row round
    const int sg   = (l & 7) ^ (l >> 3);            // global k-group for this lane
    const u16* Ag = A  + (size_t)(m0 + srow) * lda + sg * 8;
    const u16* Bg = Bt + (size_t)(n0 + srow) * ldb + sg * 8;

    auto stage = [&](int j, int buf) {
        const size_t kb = (size_t)j * 64;
        const u16* ag = Ag + kb;
        const u16* bg = Bg + kb;
        u16* al = &As[buf][w * 512];
        u16* bl = &Bs[buf][w * 512];
#pragma unroll
        for (int i = 0; i < 4; ++i) {
            load_lds16(ag + (size_t)i * 64 * lda, al + i * 4096);
            load_lds16(bg + (size_t)i * 64 * ldb, bl + i * 4096);
        }
    };

    // ---- read-side constants
    const int lr   = l & 31;
    const int kh   = l >> 5;            // 0..1
    const int keyr = lr & 7;
    const int aoff = (wm * 128 + lr) * 64;
    const int boff = (wn * 64 + lr) * 64;

    f32x16 acc[4][2];
#pragma unroll
    for (int mi = 0; mi < 4; ++mi)
#pragma unroll
        for (int ni = 0; ni < 2; ++ni)
#pragma unroll
            for (int r = 0; r < 16; ++r) acc[mi][ni][r] = 0.f;

    const int NS = K >> 6;              // K64 slabs (>= 2 for all our shapes)

    // prologue: both buffers in flight, certify slab 0 (slab 1 stays in flight)
    stage(0, 0);
    stage(1, 1);
    asm volatile("s_waitcnt vmcnt(8)" ::: "memory");
    __builtin_amdgcn_s_barrier();
    asm volatile("" ::: "memory");

    for (int j = 0; j < NS; ++j) {
        const int buf = j & 1;
        const u16* as_ = &As[buf][aoff];
        const u16* bs_ = &Bs[buf][boff];
        bf16x8 a[4][4], b[2][4];
        // phase A reads (k 0..31)
#pragma unroll
        for (int ks2 = 0; ks2 < 2; ++ks2) {
            const int sp = ((ks2 * 2 + kh) ^ keyr) * 8;
#pragma unroll
            for (int mi = 0; mi < 4; ++mi) a[mi][ks2] = *(const bf16x8*)(as_ + mi * 2048 + sp);
#pragma unroll
            for (int ni = 0; ni < 2; ++ni) b[ni][ks2] = *(const bf16x8*)(bs_ + ni * 2048 + sp);
        }
        // prefetch next slab into the other buffer (its readers retired at the
        // previous iteration's end barrier); slab 1 already staged in prologue
        if (j + 1 < NS && j > 0) stage(j + 1, buf ^ 1);
        __builtin_amdgcn_s_setprio(1);
#pragma unroll
        for (int ks2 = 0; ks2 < 2; ++ks2)
#pragma unroll
            for (int mi = 0; mi < 4; ++mi)
#pragma unroll
                for (int ni = 0; ni < 2; ++ni)
                    acc[mi][ni] = __builtin_amdgcn_mfma_f32_32x32x16_bf16(
                        a[mi][ks2], b[ni][ks2], acc[mi][ni], 0, 0, 0);
        __builtin_amdgcn_s_setprio(0);
        // phase B reads (k 32..63)
#pragma unroll
        for (int ks2 = 2; ks2 < 4; ++ks2) {
            const int sp = ((ks2 * 2 + kh) ^ keyr) * 8;
#pragma unroll
            for (int mi = 0; mi < 4; ++mi) a[mi][ks2] = *(const bf16x8*)(as_ + mi * 2048 + sp);
#pragma unroll
            for (int ni = 0; ni < 2; ++ni) b[ni][ks2] = *(const bf16x8*)(bs_ + ni * 2048 + sp);
        }
        __builtin_amdgcn_s_setprio(1);
#pragma unroll
        for (int ks2 = 2; ks2 < 4; ++ks2)
#pragma unroll
            for (int mi = 0; mi < 4; ++mi)
#pragma unroll
                for (int ni = 0; ni < 2; ++ni)
                    acc[mi][ni] = __builtin_amdgcn_mfma_f32_32x32x16_bf16(
                        a[mi][ks2], b[ni][ks2], acc[mi][ni], 0, 0, 0);
        __builtin_amdgcn_s_setprio(0);
        if (j + 1 < NS) {
            // loads were issued a full MFMA block ago -> this wait is ~free
            asm volatile("s_waitcnt vmcnt(0)" ::: "memory");
            __builtin_amdgcn_s_barrier();
            asm volatile("" ::: "memory");
        }
    }

    // epilogue
    const int colb = n0 + wn * 64 + lr;
    const int rowb = m0 + wm * 128 + 4 * kh;
#pragma unroll
    for (int mi = 0; mi < 4; ++mi) {
#pragma unroll
        for (int ni = 0; ni < 2; ++ni) {
            const int col = colb + ni * 32;
            const float bias = (EPI == 0) ? bf2f(bias3[col]) : 0.f;
#pragma unroll
            for (int r = 0; r < 16; ++r) {
                const int row = rowb + mi * 32 + (r & 3) + 8 * (r >> 2);
                C[(size_t)row * ldc + col] = f2bf(acc[mi][ni][r] * scale + bias);
            }
        }
    }
}

// -------------------------------------------------- softmax (wave-per-row)
// 4 rows/block, one 64-lane wave per row, 32 elems (64B) per lane.
// No LDS, no barriers: pure shuffle reductions.
__global__ __launch_bounds__(256) void softmax_row_kernel(u16* __restrict__ S)
{
    const int w = threadIdx.x >> 6, l = threadIdx.x & 63;
    u16* sp = S + ((size_t)blockIdx.x * 4 + w) * 2048;
    union { uint4 v; u16 h[8]; } raw[4];
    float vals[32];
#pragma unroll
    for (int c = 0; c < 4; ++c) {
        raw[c].v = *(const uint4*)(sp + l * 8 + c * 512);
#pragma unroll
        for (int i = 0; i < 8; ++i) vals[c * 8 + i] = bf2f(raw[c].h[i]);
    }
    float m = vals[0];
#pragma unroll
    for (int i = 1; i < 32; ++i) m = fmaxf(m, vals[i]);
#pragma unroll
    for (int off = 32; off > 0; off >>= 1) m = fmaxf(m, __shfl_xor(m, off));
    float e[32], s = 0.f;
#pragma unroll
    for (int i = 0; i < 32; ++i) { e[i] = __expf(vals[i] - m); s += e[i]; }
#pragma unroll
    for (int off = 32; off > 0; off >>= 1) s += __shfl_xor(s, off);
    const float rinv = 1.f / s;
#pragma unroll
    for (int c = 0; c < 4; ++c) {
        union { uint4 v; u16 h[8]; } out;
#pragma unroll
        for (int i = 0; i < 8; ++i) out.h[i] = f2bf(e[c * 8 + i] * rinv);
        *(uint4*)(sp + l * 8 + c * 512) = out.v;
    }
}

// -------------------------------------------- resid + LN (wave-per-row)
// 4 rows/block, one wave per row, 16 elems (2x16B per tensor) per lane.
// Ctx split across Q-slot (cols 0..1023) and K-slot (1024..2047) of QK2
// (PV split-K2 partial sums); summed here. Shuffle-only reduction.
__global__ __launch_bounds__(256) void resid_ln_kernel(
    const u16* __restrict__ Ctx, const u16* __restrict__ Xb,
    const u16* __restrict__ gamma, const u16* __restrict__ beta,
    void* __restrict__ Out, const u16* __restrict__ Xraw)
{
    __shared__ int sflag;
    const int fp32 = detect_fp32(Xraw, &sflag);   // one barrier, then pure-wave
    const int w = threadIdx.x >> 6, l = threadIdx.x & 63;
    const size_t row = (size_t)blockIdx.x * 4 + w;
    float v[16];
#pragma unroll
    for (int c = 0; c < 2; ++c) {
        const int off = l * 8 + c * 512;
        union { uint4 u; u16 h[8]; } c0, c1, xv;
        c0.u = *(const uint4*)(Ctx + row * 2048 + off);
        c1.u = *(const uint4*)(Ctx + row * 2048 + 1024 + off);
        xv.u = *(const uint4*)(Xb + row * 1024 + off);
#pragma unroll
        for (int i = 0; i < 8; ++i)
            v[c * 8 + i] = bf2f(c0.h[i]) + bf2f(c1.h[i]) + bf2f(xv.h[i]);
    }
    float s = 0.f, s2 = 0.f;
#pragma unroll
    for (int i = 0; i < 16; ++i) { s += v[i]; s2 += v[i] * v[i]; }
#pragma unroll
    for (int off = 32; off > 0; off >>= 1) {
        s  += __shfl_xor(s, off);
        s2 += __shfl_xor(s2, off);
    }
    const float mu  = s * (1.f / 1024.f);
    const float var = s2 * (1.f / 1024.f) - mu * mu;
    const float inv = rsqrtf(var + 1e-3f);
#pragma unroll
    for (int c = 0; c < 2; ++c) {
        const int off = l * 8 + c * 512;
        union { uint4 u; u16 h[8]; } gv, bv;
        gv.u = *(const uint4*)(gamma + off);
        bv.u = *(const uint4*)(beta + off);
        float o[8];
#pragma unroll
        for (int i = 0; i < 8; ++i)
            o[i] = (v[c * 8 + i] - mu) * inv * bf2f(gv.h[i]) + bf2f(bv.h[i]);
        if (fp32) {
            float* op = (float*)Out + row * 1024 + off;
            float4 f0 = {o[0], o[1], o[2], o[3]};
            float4 f1 = {o[4], o[5], o[6], o[7]};
            *(float4*)op       = f0;
            *(float4*)(op + 4) = f1;
        } else {
            union { uint4 u; u16 h[8]; } bo;
#pragma unroll
            for (int i = 0; i < 8; ++i) bo.h[i] = f2bf(o[i]);
            *(uint4*)((u16*)Out + row * 1024 + off) = bo.u;
        }
    }
}

// ---------------------------------------------------------------- launch
extern "C" void kernel_launch(void* const* d_in, const int* in_sizes, int n_in,
                              void* d_out, int out_size, void* d_ws, size_t ws_size,
                              hipStream_t stream)
{
    (void)in_sizes; (void)n_in; (void)out_size; (void)ws_size;
    const void* X     = d_in[0];
    const void* Wq    = d_in[1];
    const void* bq    = d_in[2];
    const void* Wk    = d_in[3];
    const void* bk    = d_in[4];
    const void* Wv    = d_in[5];
    const void* bv    = d_in[6];
    const void* gamma = d_in[7];
    const void* beta  = d_in[8];

    char* ws = (char*)d_ws;
    u16* bias5 = (u16*)(ws + 16);
    u16* Wt    = (u16*)(ws + 16384);
    u16* QK2   = (u16*)(ws + 6307840);
    u16* Xb    = (u16*)(ws + 39862272);
    u16* S4    = (u16*)(ws + 56639488);
    u16* Vt    = (u16*)(ws + 90193920);

    // 1. fused prologue
    prep_kernel<<<4869, 256, 0, stream>>>(
        X, Wq, Wk, Wv, bq, bk, bv, gamma, beta, Xb, Wt, bias5);

    // 2. proj: QK2 = Xb @ Wt(qk)^T + [bq|bk]  (1024 logical blocks)
    //          Vt  = Wv^T @ Xb^T + bv          (512 logical blocks)
    proj_kernel<<<1536, 256, 0, stream>>>(Xb, Wt, QK2, Vt, bias5);

    // 3. S4[b] = (Q_b @ K_b^T)/32   (M=N=2048, K=1024, z=4) -> 256 blocks
    gemm256r<1, 1><<<dim3(8, 8, 4), 512, 0, stream>>>(
        QK2, 2048, (size_t)2048 * 2048,
        QK2 + 1024, 2048, (size_t)2048 * 2048,
        S4, 2048, (size_t)2048 * 2048, 1024, 0.03125f, nullptr);

    // 4. softmax (wave-per-row, 8192 rows / 4 per block)
    softmax_row_kernel<<<2048, 256, 0, stream>>>(S4);

    // 5. Ctx_b = P_b @ V_b, split-K2 -> Q-slot (ks=0) + K-slot (ks=1) of QK2
    //    (M=2048, N=1024, K=1024 per half, z = 4 x 2) -> 256 blocks
    gemm256r<1, 2><<<dim3(4, 8, 8), 512, 0, stream>>>(
        S4, 2048, (size_t)2048 * 2048,
        Vt, 8192, (size_t)2048,
        QK2, 2048, (size_t)2048 * 2048, 1024, 1.f, nullptr);

    // 6. LN (wave-per-row, sums the two Ctx halves)
    resid_ln_kernel<<<2048, 256, 0, stream>>>(
        QK2, Xb, bias5 + 3 * 1024, bias5 + 4 * 1024, d_out, (const u16*)X);
}